// Round 1
// baseline (106.179 us; speedup 1.0000x reference)
//
#include <hip/hip_runtime.h>
#include <hip/hip_bf16.h>

typedef unsigned short u16;
typedef unsigned int   u32;

#define N_  16
#define C_  32
#define H_  256
#define W_  256
#define O_  32
#define WP  258                       // width padded by 1 on each side
#define XT_ELEMS (N_*H_*WP*C_)        // 33,816,576 bf16 elems (NHWC padded)
#define WT_OFF   XT_ELEMS             // weights [tap][o][c] bf16 after x
#define WT_ELEMS (9*O_*C_)            // 9216

typedef short s8v  __attribute__((ext_vector_type(8)));   // 8 bf16 (4 VGPR)
typedef float f16v __attribute__((ext_vector_type(16)));  // 32x32 acc

__device__ inline u16 f2bf(float f) {
    u32 u = __builtin_bit_cast(u32, f);
    u += 0x7FFFu + ((u >> 16) & 1u);   // RNE; inputs are finite
    return (u16)(u >> 16);
}

// ---------------- Pass 1: NCHW f32 -> padded NHWC bf16 (+ weight repack) ----
__global__ __launch_bounds__(256) void k_transpose(const float* __restrict__ x,
                                                   const float* __restrict__ wgt,
                                                   u16* __restrict__ xt) {
    __shared__ float tile[32 * 65];    // pad 65 -> conflict-free strided reads
    const int b     = blockIdx.x;      // ((n*256+h)*4 + chunk)
    const int chunk = b & 3;
    const int h     = (b >> 2) & 255;
    const int n     = b >> 10;
    const int w0    = chunk << 6;      // 64-wide chunk
    const int t     = threadIdx.x;

    // load 32c x 64w patch, coalesced along w
    {
        const int c  = t >> 3;
        const int wl = (t & 7) << 3;
        const float* src = x + (((n*32 + c)*256 + h)*256 + w0 + wl);
        float4 v0 = *(const float4*)(src);
        float4 v1 = *(const float4*)(src + 4);
        const int tb = c*65 + wl;
        tile[tb+0]=v0.x; tile[tb+1]=v0.y; tile[tb+2]=v0.z; tile[tb+3]=v0.w;
        tile[tb+4]=v1.x; tile[tb+5]=v1.y; tile[tb+6]=v1.z; tile[tb+7]=v1.w;
    }
    __syncthreads();

    // store transposed: consecutive threads = consecutive c (packed bf16x2)
    {
        const int cp = (t & 15) << 1;  // c pair base
        const int wv = t >> 4;         // 0..15
        u32* dst = (u32*)xt;
        const int rowb = (n*256 + h) * WP;
        #pragma unroll
        for (int j = 0; j < 4; ++j) {
            const int w = wv + (j << 4);
            const float f0 = tile[cp*65 + w];
            const float f1 = tile[(cp+1)*65 + w];
            const u32 p = (u32)f2bf(f0) | ((u32)f2bf(f1) << 16);
            dst[(rowb + w0 + w + 1)*16 + (t & 15)] = p;
        }
        if (chunk == 0 && t < 16) dst[rowb*16 + t] = 0u;               // wp=0 pad
        if (chunk == 3 && t < 16) dst[(rowb + 257)*16 + t] = 0u;       // wp=257 pad
    }

    // weight repack, one block only: [o][c][kh][kw] f32 -> [tap][o][c] bf16
    if (b == 0) {
        for (int idx = t; idx < WT_ELEMS; idx += 256) {
            const int tap = idx >> 10;          // 0..8
            const int o   = (idx >> 5) & 31;
            const int cc  = idx & 31;
            const int kh  = tap / 3, kw = tap - kh*3;
            xt[WT_OFF + idx] = f2bf(wgt[((o*32 + cc)*3 + kh)*3 + kw]);
        }
    }
}

// ---------------- Pass 2: implicit-GEMM conv via mfma_f32_32x32x16_bf16 -----
// Block: 256 thr = 4 waves. Block output: 32 o x 256 w x 4 rows.
// Wave: 64 px (two 32x32 acc tiles). K = 9 taps x 32 c (2 halves of 16).
__global__ __launch_bounds__(256) void k_conv(const u16* __restrict__ xt,
                                              const float* __restrict__ bias,
                                              const float* __restrict__ scale_p,
                                              float* __restrict__ out) {
    const int b    = blockIdx.x;        // n*64 + hblk
    const int n    = b >> 6;
    const int hb   = (b & 63) << 2;
    const int t    = threadIdx.x;
    const int l    = t & 63;
    const int wave = t >> 6;
    const int g    = l >> 5;            // k-group within fragment
    const int ln   = l & 31;            // M/N lane index
    const int w0   = wave << 6;         // this wave's 64-px strip

    // A fragments: W~[tap][o=ln][c = q*16 + g*8 + e], 16B contiguous
    s8v A[9][2];
    #pragma unroll
    for (int tap = 0; tap < 9; ++tap) {
        #pragma unroll
        for (int q = 0; q < 2; ++q) {
            A[tap][q] = *(const s8v*)(xt + WT_OFF + tap*1024 + ln*32 + q*16 + g*8);
        }
    }
    const float scale = scale_p[0];

    #pragma unroll
    for (int r = 0; r < 4; ++r) {
        const int h = hb + r;
        f16v acc0, acc1;
        #pragma unroll
        for (int i = 0; i < 16; ++i) { acc0[i] = 0.f; acc1[i] = 0.f; }

        #pragma unroll
        for (int kh = 0; kh < 3; ++kh) {
            const int hin = h + kh - 1;
            if (hin < 0 || hin >= 256) continue;       // uniform branch
            const u16* rowp = xt + ((n*256 + hin)*WP)*32;
            #pragma unroll
            for (int kw = 0; kw < 3; ++kw) {
                // input wp = (w + kw - 1) + 1 = w + kw  (padding folded in)
                const u16* colp = rowp + (w0 + ln + kw)*32 + g*8;
                const int tap = kh*3 + kw;
                #pragma unroll
                for (int q = 0; q < 2; ++q) {
                    const s8v b0 = *(const s8v*)(colp + q*16);
                    const s8v b1 = *(const s8v*)(colp + 1024 + q*16);  // +32 px
                    acc0 = __builtin_amdgcn_mfma_f32_32x32x16_bf16(A[tap][q], b0, acc0, 0, 0, 0);
                    acc1 = __builtin_amdgcn_mfma_f32_32x32x16_bf16(A[tap][q], b1, acc1, 0, 0, 0);
                }
            }
        }

        // epilogue: D col(px)=ln, row(o)=(reg&3)+8*(reg>>2)+4*g
        float* op = out + ((n*32)*256 + h)*256 + w0 + ln;
        #pragma unroll
        for (int reg = 0; reg < 16; ++reg) {
            const int o = (reg & 3) + 8*(reg >> 2) + 4*g;
            const float bv = bias[o];
            op[o*65536]      = scale*acc0[reg] + bv;
            op[o*65536 + 32] = scale*acc1[reg] + bv;
        }
    }
}

// ---------------- Fallback: direct fp32 conv (if d_ws too small) ------------
__global__ __launch_bounds__(256) void k_fallback(const float* __restrict__ x,
                                                  const float* __restrict__ wgt,
                                                  const float* __restrict__ bias,
                                                  const float* __restrict__ scale_p,
                                                  float* __restrict__ out) {
    const int b = blockIdx.x;           // (n*32 + o)*256 + h
    const int h = b & 255;
    const int o = (b >> 8) & 31;
    const int n = b >> 13;
    const int w = threadIdx.x;
    float acc = 0.f;
    for (int c = 0; c < 32; ++c) {
        const float* xp = x + ((n*32 + c)*256 + h)*256;
        const float* wp = wgt + (o*32 + c)*9;
        #pragma unroll
        for (int kh = 0; kh < 3; ++kh) {
            const int hin = h + kh - 1;
            if (hin < 0 || hin >= 256) continue;
            const float* xr = xp + (kh - 1)*256;
            #pragma unroll
            for (int kw = 0; kw < 3; ++kw) {
                const int win = w + kw - 1;
                if (win < 0 || win >= 256) continue;
                acc += xr[win] * wp[kh*3 + kw];
            }
        }
    }
    out[b*256 + w] = scale_p[0]*acc + bias[o];
}

extern "C" void kernel_launch(void* const* d_in, const int* in_sizes, int n_in,
                              void* d_out, int out_size, void* d_ws, size_t ws_size,
                              hipStream_t stream) {
    const float* x     = (const float*)d_in[0];
    const float* wgt   = (const float*)d_in[1];
    const float* bias  = (const float*)d_in[2];
    const float* scale = (const float*)d_in[3];
    float* out = (float*)d_out;

    const size_t need = (size_t)(XT_ELEMS + WT_ELEMS) * sizeof(u16);  // ~67.7 MB
    if (ws_size >= need) {
        u16* xt = (u16*)d_ws;
        k_transpose<<<dim3(16384), dim3(256), 0, stream>>>(x, wgt, xt);
        k_conv<<<dim3(1024), dim3(256), 0, stream>>>(xt, bias, scale, out);
    } else {
        k_fallback<<<dim3(131072), dim3(256), 0, stream>>>(x, wgt, bias, scale, out);
    }
}